// Round 4
// baseline (2596.044 us; speedup 1.0000x reference)
//
#include <hip/hip_runtime.h>
#include <hip/hip_bf16.h>

#define NROWS 16384
#define XD 1024
#define DD 4096

typedef __attribute__((ext_vector_type(8))) short short8;
typedef __attribute__((ext_vector_type(4))) float f32x4;

__device__ __forceinline__ unsigned short f2bf(float f) {
  unsigned int u = __builtin_bit_cast(unsigned int, f);
  u += 0x7fffu + ((u >> 16) & 1u);
  return (unsigned short)(u >> 16);
}

__device__ __forceinline__ void load_lds16(const void* g, void* l) {
  __builtin_amdgcn_global_load_lds((const __attribute__((address_space(1))) void*)g,
                                   (__attribute__((address_space(3))) void*)l, 16, 0, 0);
}

// ---------------- row mask ----------------
__global__ __launch_bounds__(256) void mask_kernel(const float* __restrict__ u,
                                                   const float* __restrict__ v,
                                                   float* __restrict__ w) {
  int r = blockIdx.x;
  int t = threadIdx.x;
  const f32x4* up = (const f32x4*)(u + (size_t)r * XD);
  const f32x4* vp = (const f32x4*)(v + (size_t)r * DD);
  f32x4 a = up[t];
  int fu = __syncthreads_or((a.x != 0.f) | (a.y != 0.f) | (a.z != 0.f) | (a.w != 0.f));
  int fv = 0;
#pragma unroll
  for (int it = 0; it < DD / (256 * 4); ++it) {
    if (!fv) {
      f32x4 b = vp[it * 256 + t];
      fv = __syncthreads_or((b.x != 0.f) | (b.y != 0.f) | (b.z != 0.f) | (b.w != 0.f));
    }
  }
  if (t == 0) w[r] = (fu && fv) ? 1.f : 0.f;
}

// ---------------- k = sum(w) ----------------
__global__ __launch_bounds__(256) void ksum_kernel(const float* __restrict__ w,
                                                   float* __restrict__ kout) {
  __shared__ float sm[256];
  float s = 0.f;
  for (int i = threadIdx.x; i < NROWS; i += 256) s += w[i];
  sm[threadIdx.x] = s;
  __syncthreads();
  for (int st = 128; st > 0; st >>= 1) {
    if (threadIdx.x < st) sm[threadIdx.x] += sm[threadIdx.x + st];
    __syncthreads();
  }
  if (threadIdx.x == 0) kout[0] = sm[0];
}

// ---------------- column stats ----------------
__global__ __launch_bounds__(256) void colstats_partial(const float* __restrict__ X, int cols,
                                                        const float* __restrict__ w,
                                                        float* __restrict__ p1,
                                                        float* __restrict__ p2) {
  int c = blockIdx.x * 256 + threadIdx.x;
  int r0 = blockIdx.y * (NROWS / 64);
  float s1 = 0.f, s2 = 0.f;
  for (int r = r0; r < r0 + NROWS / 64; ++r) {
    float wr = w[r];
    float x = X[(size_t)r * cols + c];
    float xw = x * wr;
    s1 += xw;
    s2 += xw * x;
  }
  p1[(size_t)blockIdx.y * cols + c] = s1;
  p2[(size_t)blockIdx.y * cols + c] = s2;
}

__global__ __launch_bounds__(256) void colstats_final(const float* __restrict__ p1,
                                                      const float* __restrict__ p2,
                                                      const float* __restrict__ kptr, int cols,
                                                      float* __restrict__ mean,
                                                      float* __restrict__ inv) {
  int c = blockIdx.x * 256 + threadIdx.x;
  float s1 = 0.f, s2 = 0.f;
  for (int j = 0; j < 64; ++j) {
    s1 += p1[(size_t)j * cols + c];
    s2 += p2[(size_t)j * cols + c];
  }
  float k = kptr[0];
  float m = s1 / k;
  float s = s2 - s1 * s1 / k;
  float sd = sqrtf(fmaxf(s, 0.f) / (k - 1.f));
  mean[c] = m;
  inv[c] = 1.f / (sd + 1e-7f);
}

// ---------------- weight transpose+convert: W[R][C] f32 -> T[C][R] bf16 ----------------
__global__ __launch_bounds__(256) void wt_kernel(const float* __restrict__ W, int R, int C,
                                                 unsigned short* __restrict__ T) {
  __shared__ unsigned short tile[64][65];
  int r0 = blockIdx.x * 64, c0 = blockIdx.y * 64;
  int tr = threadIdx.x >> 2;
  int tc = (threadIdx.x & 3) * 16;
  const float* src = W + (size_t)(r0 + tr) * C + c0 + tc;
#pragma unroll
  for (int i = 0; i < 16; i += 4) {
    f32x4 v4 = *(const f32x4*)(src + i);
    tile[tr][tc + i + 0] = f2bf(v4.x);
    tile[tr][tc + i + 1] = f2bf(v4.y);
    tile[tr][tc + i + 2] = f2bf(v4.z);
    tile[tr][tc + i + 3] = f2bf(v4.w);
  }
  __syncthreads();
  unsigned short* dst = T + (size_t)(c0 + tr) * R + r0 + tc;
  short8 o0, o1;
#pragma unroll
  for (int i = 0; i < 8; ++i) o0[i] = (short)tile[tc + i][tr];
#pragma unroll
  for (int i = 0; i < 8; ++i) o1[i] = (short)tile[tc + 8 + i][tr];
  *(short8*)(dst) = o0;
  *(short8*)(dst + 8) = o1;
}

// ---------------- normalize chunk: bf16 out ----------------
__global__ __launch_bounds__(256) void norm_kernel(const float* __restrict__ X,
                                                   const float* __restrict__ mean,
                                                   const float* __restrict__ inv,
                                                   unsigned short* __restrict__ O,
                                                   int colmask, size_t n8) {
  size_t stride = (size_t)gridDim.x * 256;
  for (size_t i = (size_t)blockIdx.x * 256 + threadIdx.x; i < n8; i += stride) {
    int c8 = (int)(i & (size_t)colmask);
    const float* xp = X + i * 8;
    f32x4 a = *(const f32x4*)xp;
    f32x4 b = *(const f32x4*)(xp + 4);
    f32x4 m0 = *(const f32x4*)(mean + c8 * 8);
    f32x4 m1 = *(const f32x4*)(mean + c8 * 8 + 4);
    f32x4 i0 = *(const f32x4*)(inv + c8 * 8);
    f32x4 i1 = *(const f32x4*)(inv + c8 * 8 + 4);
    short8 p;
    p[0] = (short)f2bf((a.x - m0.x) * i0.x);
    p[1] = (short)f2bf((a.y - m0.y) * i0.y);
    p[2] = (short)f2bf((a.z - m0.z) * i0.z);
    p[3] = (short)f2bf((a.w - m0.w) * i0.w);
    p[4] = (short)f2bf((b.x - m1.x) * i1.x);
    p[5] = (short)f2bf((b.y - m1.y) * i1.y);
    p[6] = (short)f2bf((b.z - m1.z) * i1.z);
    p[7] = (short)f2bf((b.w - m1.w) * i1.w);
    *(short8*)(O + i * 8) = p;
  }
}

// ---------------- 256x256 GEMM, BK=32, 4-deep pipelined LDS, counted vmcnt ----------------
// C[M][N] = A[M][K] (bf16 k-contig) x Bt[N][K]^T (bf16 k-contig)
// LDS per buf per operand: 256 rows x 32k x 2B = 16 KiB, row-pair per 128B line,
// 16B slot s within a row holds global k-slot s ^ ((row>>1)&3)  (XOR involution).
// EPI 0: H = relu(C + bias) -> bf16 ;  EPI 1: O = (C + bias) * wrow -> f32
template <int EPI>
__global__ __launch_bounds__(512, 2) void gemm8p(const unsigned short* __restrict__ A,
                                                 const unsigned short* __restrict__ Bt,
                                                 const float* __restrict__ bias,
                                                 const float* __restrict__ wrow,
                                                 void* __restrict__ OutP,
                                                 int N, int K) {
  __shared__ char lds[131072];  // A bufs 0..65535 (4 x 16KiB), B bufs 65536..131071
  const int tid = threadIdx.x;
  const int lane = tid & 63;
  const int wave = tid >> 6;   // 0..7
  const int wr = wave >> 2;    // m half
  const int wc = wave & 3;     // n quarter

  const int gn = N >> 8;
  const int nwg = gridDim.x;
  const int bid = blockIdx.x;
  const int sw = (nwg & 7) ? bid : ((bid & 7) * (nwg >> 3) + (bid >> 3));
  const int m0 = (sw / gn) << 8;
  const int n0 = (sw % gn) << 8;

  const int NT = K >> 5;

  // staging thread-constants: chunk c = g*512 + wave*64 + lane (16B units)
  const int rl = 2 * (lane >> 3) + ((lane >> 2) & 1);  // row within 16-row group
  const int sl = (lane & 3) ^ ((lane >> 3) & 3);       // pre-swizzled global k-slot

  // fragment-read constants: row r in tile, k-group = lane>>4
  const int fr = lane & 15;
  const int frag_off =
      (fr >> 1) * 128 + (fr & 1) * 64 + (((lane >> 4) ^ ((fr >> 1) & 3)) << 4);

#define STAGE_G(T, G)                                                               \
  {                                                                                 \
    const int k0_ = (T) << 5;                                                       \
    const int r_ = (G) * 128 + wave * 16 + rl;                                      \
    const int co_ = ((G) * 512 + wave * 64) * 16;                                   \
    const int bo_ = ((T) & 3) * 16384;                                              \
    load_lds16(A + (size_t)(m0 + r_) * K + k0_ + sl * 8, lds + bo_ + co_);          \
    load_lds16(Bt + (size_t)(n0 + r_) * K + k0_ + sl * 8, lds + 65536 + bo_ + co_); \
  }

  f32x4 acc[8][4] = {};

  // prologue: stage tiles 0,1,2 (4 loads/thread each, tile-0 loads oldest)
  STAGE_G(0, 0); STAGE_G(0, 1);
  STAGE_G(1, 0); STAGE_G(1, 1);
  STAGE_G(2, 0); STAGE_G(2, 1);
  asm volatile("s_waitcnt vmcnt(8)" ::: "memory");  // tile 0 landed
  __builtin_amdgcn_sched_barrier(0);
  __builtin_amdgcn_s_barrier();

  short8 afr[4], bfr[4];
  for (int t = 0; t < NT; ++t) {
    const int bo = (t & 3) * 16384;
    const char* Abase = lds + bo + wr * 8192;
    const char* Bbase = lds + 65536 + bo + wc * 4096;

    // ---- phase 0: frags (B all 4, A 0-3) + prefetch group0 of t+3 ----
#pragma unroll
    for (int g = 0; g < 4; ++g) bfr[g] = *(const short8*)(Bbase + g * 1024 + frag_off);
#pragma unroll
    for (int f = 0; f < 4; ++f) afr[f] = *(const short8*)(Abase + f * 1024 + frag_off);
    if (t + 3 < NT) STAGE_G(t + 3, 0);
    __builtin_amdgcn_s_barrier();
    asm volatile("s_waitcnt lgkmcnt(0)" ::: "memory");
    __builtin_amdgcn_sched_barrier(0);
    __builtin_amdgcn_s_setprio(1);
#pragma unroll
    for (int f = 0; f < 4; ++f)
#pragma unroll
      for (int g = 0; g < 4; ++g)
        acc[f][g] = __builtin_amdgcn_mfma_f32_16x16x32_bf16(afr[f], bfr[g], acc[f][g], 0, 0, 0);
    __builtin_amdgcn_s_setprio(0);
    __builtin_amdgcn_s_barrier();

    // ---- phase 1: frags (A 4-7) + prefetch group1 of t+3 + counted vmcnt ----
#pragma unroll
    for (int f = 0; f < 4; ++f) afr[f] = *(const short8*)(Abase + (4 + f) * 1024 + frag_off);
    if (t + 3 < NT) {
      STAGE_G(t + 3, 1);
      asm volatile("s_waitcnt vmcnt(8)" ::: "memory");  // tile t+1 landed
    } else if (t == NT - 3) {
      asm volatile("s_waitcnt vmcnt(4)" ::: "memory");
    } else if (t == NT - 2) {
      asm volatile("s_waitcnt vmcnt(0)" ::: "memory");
    }
    __builtin_amdgcn_sched_barrier(0);
    __builtin_amdgcn_s_barrier();
    asm volatile("s_waitcnt lgkmcnt(0)" ::: "memory");
    __builtin_amdgcn_sched_barrier(0);
    __builtin_amdgcn_s_setprio(1);
#pragma unroll
    for (int f = 0; f < 4; ++f)
#pragma unroll
      for (int g = 0; g < 4; ++g)
        acc[4 + f][g] =
            __builtin_amdgcn_mfma_f32_16x16x32_bf16(afr[f], bfr[g], acc[4 + f][g], 0, 0, 0);
    __builtin_amdgcn_s_setprio(0);
    __builtin_amdgcn_s_barrier();
  }
#undef STAGE_G

  const int colloc = wc * 64 + fr;
  const int rowb = wr * 128 + ((lane >> 4) << 2);
  if (EPI == 0) {
    unsigned short* H = (unsigned short*)OutP;
#pragma unroll
    for (int f = 0; f < 8; ++f)
#pragma unroll
      for (int g = 0; g < 4; ++g) {
        const int c = n0 + colloc + g * 16;
        const float b = bias[c];
#pragma unroll
        for (int r = 0; r < 4; ++r) {
          const int row = m0 + rowb + f * 16 + r;
          H[(size_t)row * N + c] = f2bf(fmaxf(acc[f][g][r] + b, 0.f));
        }
      }
  } else {
    float* O = (float*)OutP;
#pragma unroll
    for (int f = 0; f < 8; ++f)
#pragma unroll
      for (int g = 0; g < 4; ++g) {
        const int c = n0 + colloc + g * 16;
        const float b = bias[c];
#pragma unroll
        for (int r = 0; r < 4; ++r) {
          const int row = m0 + rowb + f * 16 + r;
          O[(size_t)row * N + c] = (acc[f][g][r] + b) * wrow[row];
        }
      }
  }
}

extern "C" void kernel_launch(void* const* d_in, const int* in_sizes, int n_in,
                              void* d_out, int out_size, void* d_ws, size_t ws_size,
                              hipStream_t stream) {
  const float* u    = (const float*)d_in[0];
  const float* v    = (const float*)d_in[1];
  const float* u_W1 = (const float*)d_in[2];
  const float* u_b1 = (const float*)d_in[3];
  const float* u_W2 = (const float*)d_in[4];
  const float* u_b2 = (const float*)d_in[5];
  const float* v_W1 = (const float*)d_in[6];
  const float* v_b1 = (const float*)d_in[7];
  const float* v_W2 = (const float*)d_in[8];
  const float* v_b2 = (const float*)d_in[9];
  float* out1 = (float*)d_out;
  float* out2 = out1 + (size_t)NROWS * XD;

  float* wsf = (float*)d_ws;
  size_t off = 0;
  float* w_     = wsf + off; off += NROWS;
  float* kv     = wsf + off; off += 16;
  float* u_mean = wsf + off; off += XD;
  float* u_inv  = wsf + off; off += XD;
  float* v_mean = wsf + off; off += DD;
  float* v_inv  = wsf + off; off += DD;
  float* p1u    = wsf + off; off += 64 * XD;
  float* p2u    = wsf + off; off += 64 * XD;
  float* p1v    = wsf + off; off += 64 * DD;
  float* p2v    = wsf + off; off += 64 * DD;

  size_t boff = (off * 4 + 255) & ~(size_t)255;
  unsigned short* W1Tu = (unsigned short*)((char*)d_ws + boff); boff += (size_t)(2 * XD) * XD * 2;
  unsigned short* W2Tu = (unsigned short*)((char*)d_ws + boff); boff += (size_t)XD * (2 * XD) * 2;
  unsigned short* W1Tv = (unsigned short*)((char*)d_ws + boff); boff += (size_t)(2 * DD) * DD * 2;
  unsigned short* W2Tv = (unsigned short*)((char*)d_ws + boff); boff += (size_t)DD * (2 * DD) * 2;
  size_t fixedB = (boff + 255) & ~(size_t)255;

  // choose chunk sizes by fit + grid-utilization cost
  static const int chs[7] = {16384, 8192, 4096, 2048, 1024, 512, 256};
  int CHu = 256, CHv = 256;
  double best = 1e30;
  for (int a = 0; a < 7; ++a)
    for (int b = 0; b < 7; ++b) {
      int cu = chs[a], cv = chs[b];
      size_t need = fixedB + (size_t)cu * XD * 6 + (size_t)cv * DD * 6 + 1024;
      if (need > ws_size) continue;
      auto util = [](int nwg) { return nwg >= 256 ? 1.0 : nwg / 256.0; };
      double cost = 68.75 / util((cu >> 8) * 8) + 68.75 / util((cu >> 8) * 4) +
                    550.0 / util((cv >> 8) * 32) + 550.0 / util((cv >> 8) * 16);
      if (cost < best) { best = cost; CHu = cu; CHv = cv; }
    }

  size_t p = fixedB;
  unsigned short* unc  = (unsigned short*)((char*)d_ws + p); p += (size_t)CHu * XD * 2;
  unsigned short* uhid = (unsigned short*)((char*)d_ws + p); p += (size_t)CHu * (2 * XD) * 2;
  unsigned short* vnc  = (unsigned short*)((char*)d_ws + p); p += (size_t)CHv * DD * 2;
  unsigned short* vhid = (unsigned short*)((char*)d_ws + p);

  // ---- stats ----
  mask_kernel<<<NROWS, 256, 0, stream>>>(u, v, w_);
  ksum_kernel<<<1, 256, 0, stream>>>(w_, kv);
  colstats_partial<<<dim3(XD / 256, 64), 256, 0, stream>>>(u, XD, w_, p1u, p2u);
  colstats_partial<<<dim3(DD / 256, 64), 256, 0, stream>>>(v, DD, w_, p1v, p2v);
  colstats_final<<<XD / 256, 256, 0, stream>>>(p1u, p2u, kv, XD, u_mean, u_inv);
  colstats_final<<<DD / 256, 256, 0, stream>>>(p1v, p2v, kv, DD, v_mean, v_inv);

  // ---- weights -> bf16 transposed ----
  wt_kernel<<<dim3(XD / 64, (2 * XD) / 64), 256, 0, stream>>>(u_W1, XD, 2 * XD, W1Tu);
  wt_kernel<<<dim3((2 * XD) / 64, XD / 64), 256, 0, stream>>>(u_W2, 2 * XD, XD, W2Tu);
  wt_kernel<<<dim3(DD / 64, (2 * DD) / 64), 256, 0, stream>>>(v_W1, DD, 2 * DD, W1Tv);
  wt_kernel<<<dim3((2 * DD) / 64, DD / 64), 256, 0, stream>>>(v_W2, 2 * DD, DD, W2Tv);

  // ---- u path ----
  for (int r0 = 0; r0 < NROWS; r0 += CHu) {
    size_t n8 = (size_t)CHu * XD / 8;
    int ng = (int)(n8 / 256 < 2048 ? n8 / 256 : 2048);
    norm_kernel<<<ng, 256, 0, stream>>>(u + (size_t)r0 * XD, u_mean, u_inv, unc, XD / 8 - 1, n8);
    gemm8p<0><<<(CHu >> 8) * ((2 * XD) >> 8), 512, 0, stream>>>(unc, W1Tu, u_b1, nullptr, uhid,
                                                                2 * XD, XD);
    gemm8p<1><<<(CHu >> 8) * (XD >> 8), 512, 0, stream>>>(uhid, W2Tu, u_b2, w_ + r0,
                                                          out1 + (size_t)r0 * XD, XD, 2 * XD);
  }
  // ---- v path ----
  for (int r0 = 0; r0 < NROWS; r0 += CHv) {
    size_t n8 = (size_t)CHv * DD / 8;
    int ng = (int)(n8 / 256 < 2048 ? n8 / 256 : 2048);
    norm_kernel<<<ng, 256, 0, stream>>>(v + (size_t)r0 * DD, v_mean, v_inv, vnc, DD / 8 - 1, n8);
    gemm8p<0><<<(CHv >> 8) * ((2 * DD) >> 8), 512, 0, stream>>>(vnc, W1Tv, v_b1, nullptr, vhid,
                                                                2 * DD, DD);
    gemm8p<1><<<(CHv >> 8) * (DD >> 8), 512, 0, stream>>>(vhid, W2Tv, v_b2, w_ + r0,
                                                          out2 + (size_t)r0 * DD, DD, 2 * DD);
  }
}

// Round 5
// 2300.642 us; speedup vs baseline: 1.1284x; 1.1284x over previous
//
#include <hip/hip_runtime.h>
#include <hip/hip_bf16.h>

#define NROWS 16384
#define XD 1024
#define DD 4096

typedef __attribute__((ext_vector_type(8))) short short8;
typedef __attribute__((ext_vector_type(4))) float f32x4;

__device__ __forceinline__ unsigned short f2bf(float f) {
  unsigned int u = __builtin_bit_cast(unsigned int, f);
  u += 0x7fffu + ((u >> 16) & 1u);
  return (unsigned short)(u >> 16);
}

__device__ __forceinline__ void load_lds16(const void* g, void* l) {
  __builtin_amdgcn_global_load_lds((const __attribute__((address_space(1))) void*)g,
                                   (__attribute__((address_space(3))) void*)l, 16, 0, 0);
}

// ---------------- row mask ----------------
__global__ __launch_bounds__(256) void mask_kernel(const float* __restrict__ u,
                                                   const float* __restrict__ v,
                                                   float* __restrict__ w) {
  int r = blockIdx.x;
  int t = threadIdx.x;
  const f32x4* up = (const f32x4*)(u + (size_t)r * XD);
  const f32x4* vp = (const f32x4*)(v + (size_t)r * DD);
  f32x4 a = up[t];
  int fu = __syncthreads_or((a.x != 0.f) | (a.y != 0.f) | (a.z != 0.f) | (a.w != 0.f));
  int fv = 0;
#pragma unroll
  for (int it = 0; it < DD / (256 * 4); ++it) {
    if (!fv) {
      f32x4 b = vp[it * 256 + t];
      fv = __syncthreads_or((b.x != 0.f) | (b.y != 0.f) | (b.z != 0.f) | (b.w != 0.f));
    }
  }
  if (t == 0) w[r] = (fu && fv) ? 1.f : 0.f;
}

// ---------------- k = sum(w) ----------------
__global__ __launch_bounds__(256) void ksum_kernel(const float* __restrict__ w,
                                                   float* __restrict__ kout) {
  __shared__ float sm[256];
  float s = 0.f;
  for (int i = threadIdx.x; i < NROWS; i += 256) s += w[i];
  sm[threadIdx.x] = s;
  __syncthreads();
  for (int st = 128; st > 0; st >>= 1) {
    if (threadIdx.x < st) sm[threadIdx.x] += sm[threadIdx.x + st];
    __syncthreads();
  }
  if (threadIdx.x == 0) kout[0] = sm[0];
}

// ---------------- column stats ----------------
__global__ __launch_bounds__(256) void colstats_partial(const float* __restrict__ X, int cols,
                                                        const float* __restrict__ w,
                                                        float* __restrict__ p1,
                                                        float* __restrict__ p2) {
  int c = blockIdx.x * 256 + threadIdx.x;
  int r0 = blockIdx.y * (NROWS / 64);
  float s1 = 0.f, s2 = 0.f;
  for (int r = r0; r < r0 + NROWS / 64; ++r) {
    float wr = w[r];
    float x = X[(size_t)r * cols + c];
    float xw = x * wr;
    s1 += xw;
    s2 += xw * x;
  }
  p1[(size_t)blockIdx.y * cols + c] = s1;
  p2[(size_t)blockIdx.y * cols + c] = s2;
}

__global__ __launch_bounds__(256) void colstats_final(const float* __restrict__ p1,
                                                      const float* __restrict__ p2,
                                                      const float* __restrict__ kptr, int cols,
                                                      float* __restrict__ mean,
                                                      float* __restrict__ inv) {
  int c = blockIdx.x * 256 + threadIdx.x;
  float s1 = 0.f, s2 = 0.f;
  for (int j = 0; j < 64; ++j) {
    s1 += p1[(size_t)j * cols + c];
    s2 += p2[(size_t)j * cols + c];
  }
  float k = kptr[0];
  float m = s1 / k;
  float s = s2 - s1 * s1 / k;
  float sd = sqrtf(fmaxf(s, 0.f) / (k - 1.f));
  mean[c] = m;
  inv[c] = 1.f / (sd + 1e-7f);
}

// ---------------- weight transpose+convert: W[R][C] f32 -> T[C][R] bf16 ----------------
__global__ __launch_bounds__(256) void wt_kernel(const float* __restrict__ W, int R, int C,
                                                 unsigned short* __restrict__ T) {
  __shared__ unsigned short tile[64][65];
  int r0 = blockIdx.x * 64, c0 = blockIdx.y * 64;
  int tr = threadIdx.x >> 2;
  int tc = (threadIdx.x & 3) * 16;
  const float* src = W + (size_t)(r0 + tr) * C + c0 + tc;
#pragma unroll
  for (int i = 0; i < 16; i += 4) {
    f32x4 v4 = *(const f32x4*)(src + i);
    tile[tr][tc + i + 0] = f2bf(v4.x);
    tile[tr][tc + i + 1] = f2bf(v4.y);
    tile[tr][tc + i + 2] = f2bf(v4.z);
    tile[tr][tc + i + 3] = f2bf(v4.w);
  }
  __syncthreads();
  unsigned short* dst = T + (size_t)(c0 + tr) * R + r0 + tc;
  short8 o0, o1;
#pragma unroll
  for (int i = 0; i < 8; ++i) o0[i] = (short)tile[tc + i][tr];
#pragma unroll
  for (int i = 0; i < 8; ++i) o1[i] = (short)tile[tc + 8 + i][tr];
  *(short8*)(dst) = o0;
  *(short8*)(dst + 8) = o1;
}

// ---------------- normalize chunk: bf16 out ----------------
__global__ __launch_bounds__(256) void norm_kernel(const float* __restrict__ X,
                                                   const float* __restrict__ mean,
                                                   const float* __restrict__ inv,
                                                   unsigned short* __restrict__ O,
                                                   int colmask, size_t n8) {
  size_t stride = (size_t)gridDim.x * 256;
  for (size_t i = (size_t)blockIdx.x * 256 + threadIdx.x; i < n8; i += stride) {
    int c8 = (int)(i & (size_t)colmask);
    const float* xp = X + i * 8;
    f32x4 a = *(const f32x4*)xp;
    f32x4 b = *(const f32x4*)(xp + 4);
    f32x4 m0 = *(const f32x4*)(mean + c8 * 8);
    f32x4 m1 = *(const f32x4*)(mean + c8 * 8 + 4);
    f32x4 i0 = *(const f32x4*)(inv + c8 * 8);
    f32x4 i1 = *(const f32x4*)(inv + c8 * 8 + 4);
    short8 p;
    p[0] = (short)f2bf((a.x - m0.x) * i0.x);
    p[1] = (short)f2bf((a.y - m0.y) * i0.y);
    p[2] = (short)f2bf((a.z - m0.z) * i0.z);
    p[3] = (short)f2bf((a.w - m0.w) * i0.w);
    p[4] = (short)f2bf((b.x - m1.x) * i1.x);
    p[5] = (short)f2bf((b.y - m1.y) * i1.y);
    p[6] = (short)f2bf((b.z - m1.z) * i1.z);
    p[7] = (short)f2bf((b.w - m1.w) * i1.w);
    *(short8*)(O + i * 8) = p;
  }
}

// ---------------- 256x256 tiled GEMM, BK=64, 8 waves, dbuf LDS, swizzled ----------------
// C[M][N] = A[M][K] (bf16, k-contig) x Bt[N][K]^T (bf16, k-contig)
// Block->tile map: XCD-contiguous ranges tiled as 4m x 8n supertiles so the 32
// co-resident CUs of one XCD share A/B panels in L2.
// EPI 0: H = relu(C + bias) -> bf16 ;  EPI 1: O = (C + bias) * wrow -> f32
template <int EPI>
__global__ __launch_bounds__(512, 2) void gemm8p(const unsigned short* __restrict__ A,
                                                 const unsigned short* __restrict__ Bt,
                                                 const float* __restrict__ bias,
                                                 const float* __restrict__ wrow,
                                                 void* __restrict__ OutP,
                                                 int N, int K) {
  __shared__ char lds[131072];  // A: [2][256][64]bf16 @0, B: same @65536
  const int tid = threadIdx.x;
  const int lane = tid & 63;
  const int wave = tid >> 6;     // 0..7
  const int wr = wave >> 2;      // 0..1 (m half)
  const int wc = wave & 3;       // 0..3 (n quarter)

  const int gn = N >> 8;
  const int nwg = gridDim.x;
  const int gm = nwg / gn;
  const int bid = blockIdx.x;
  // XCD-contiguous reorder
  const int sw = (nwg & 7) ? bid : ((bid & 7) * (nwg >> 3) + (bid >> 3));
  // supertile map: SW_W x SW_H = 32 blocks (one XCD's worth of CUs)
  const int SW_W = (gn >= 8) ? 8 : gn;
  const int SW_H = 32 / SW_W;
  int mt, nt;
  if ((gn % SW_W) == 0 && (gm % SW_H) == 0) {
    const int stn = gn / SW_W;
    const int st = sw >> 5;           // /32
    const int wi = sw & 31;
    mt = (st / stn) * SW_H + wi / SW_W;
    nt = (st % stn) * SW_W + wi % SW_W;
  } else {
    mt = sw / gn;
    nt = sw % gn;
  }
  const int m0 = mt << 8;
  const int n0 = nt << 8;

  // staging: chunk ca = i*8+wave covers rows ca*8..ca*8+7; source col pre-swizzled
  const int srow = lane >> 3;
  const int scol = ((lane & 7) ^ srow) << 3;

  const int NT = K >> 6;
  f32x4 acc[8][4] = {};

  char* const Abase = lds + wr * 16384;
  char* const Bbase = lds + 65536 + (wc >> 1) * 16384;
  const int bcol = (wc & 1) * 64;
  const int fr = lane & 15;             // row/col within fragment
  const int kbyte = (lane >> 4) << 4;   // k byte offset within 64B half

#define STAGE(T, BUF)                                                              \
  {                                                                                \
    const int k0_ = (T) << 6;                                                      \
    _Pragma("unroll") for (int i = 0; i < 4; ++i) {                                \
      const int row_ = i * 64 + wave * 8 + srow;                                   \
      const int co_ = (i * 8 + wave) * 1024;                                       \
      load_lds16(A + (size_t)(m0 + row_) * K + k0_ + scol, lds + (BUF)*32768 + co_); \
      load_lds16(Bt + (size_t)(n0 + row_) * K + k0_ + scol,                        \
                 lds + 65536 + (BUF)*32768 + co_);                                 \
    }                                                                              \
  }

  STAGE(0, 0);
  __syncthreads();

  for (int t = 0; t < NT; ++t) {
    const int buf = t & 1;
    const int ab = buf * 32768;
    if (t + 1 < NT) STAGE(t + 1, buf ^ 1);

    // B fragments: 4 n-frags x 2 k-steps
    short8 bfr[2][4];
#pragma unroll
    for (int s = 0; s < 2; ++s)
#pragma unroll
      for (int g = 0; g < 4; ++g) {
        const int r = bcol + g * 16 + fr;
        const int kb = s * 64 + kbyte;
        bfr[s][g] = *(const short8*)(Bbase + ab + r * 128 + (kb ^ ((r & 7) << 4)));
      }

    // A fragments ping-pong: pairs of 2 m-frags, prefetched one quadrant ahead
    short8 afA[2][2], afB[2][2];
#pragma unroll
    for (int p = 0; p < 2; ++p)
#pragma unroll
      for (int s = 0; s < 2; ++s) {
        const int r = p * 16 + fr;
        const int kb = s * 64 + kbyte;
        afA[p][s] = *(const short8*)(Abase + ab + r * 128 + (kb ^ ((r & 7) << 4)));
      }
#pragma unroll
    for (int q = 0; q < 4; ++q) {
      if (q < 3) {
#pragma unroll
        for (int p = 0; p < 2; ++p)
#pragma unroll
          for (int s = 0; s < 2; ++s) {
            const int r = ((q + 1) * 2 + p) * 16 + fr;
            const int kb = s * 64 + kbyte;
            short8 vf = *(const short8*)(Abase + ab + r * 128 + (kb ^ ((r & 7) << 4)));
            if (q & 1) afA[p][s] = vf; else afB[p][s] = vf;
          }
      }
      __builtin_amdgcn_s_setprio(1);
#pragma unroll
      for (int p = 0; p < 2; ++p)
#pragma unroll
        for (int s = 0; s < 2; ++s)
#pragma unroll
          for (int g = 0; g < 4; ++g) {
            const short8 av = (q & 1) ? afB[p][s] : afA[p][s];
            acc[q * 2 + p][g] =
                __builtin_amdgcn_mfma_f32_16x16x32_bf16(av, bfr[s][g], acc[q * 2 + p][g], 0, 0, 0);
          }
      __builtin_amdgcn_s_setprio(0);
    }
    __syncthreads();
  }

  const int colloc = wc * 64 + fr;
  const int rowb = wr * 128 + ((lane >> 4) << 2);
  if (EPI == 0) {
    unsigned short* H = (unsigned short*)OutP;
#pragma unroll
    for (int f = 0; f < 8; ++f)
#pragma unroll
      for (int g = 0; g < 4; ++g) {
        const int c = n0 + colloc + g * 16;
        const float b = bias[c];
#pragma unroll
        for (int r = 0; r < 4; ++r) {
          const int row = m0 + rowb + f * 16 + r;
          H[(size_t)row * N + c] = f2bf(fmaxf(acc[f][g][r] + b, 0.f));
        }
      }
  } else {
    float* O = (float*)OutP;
#pragma unroll
    for (int f = 0; f < 8; ++f)
#pragma unroll
      for (int g = 0; g < 4; ++g) {
        const int c = n0 + colloc + g * 16;
        const float b = bias[c];
#pragma unroll
        for (int r = 0; r < 4; ++r) {
          const int row = m0 + rowb + f * 16 + r;
          O[(size_t)row * N + c] = (acc[f][g][r] + b) * wrow[row];
        }
      }
  }
#undef STAGE
}

extern "C" void kernel_launch(void* const* d_in, const int* in_sizes, int n_in,
                              void* d_out, int out_size, void* d_ws, size_t ws_size,
                              hipStream_t stream) {
  const float* u    = (const float*)d_in[0];
  const float* v    = (const float*)d_in[1];
  const float* u_W1 = (const float*)d_in[2];
  const float* u_b1 = (const float*)d_in[3];
  const float* u_W2 = (const float*)d_in[4];
  const float* u_b2 = (const float*)d_in[5];
  const float* v_W1 = (const float*)d_in[6];
  const float* v_b1 = (const float*)d_in[7];
  const float* v_W2 = (const float*)d_in[8];
  const float* v_b2 = (const float*)d_in[9];
  float* out1 = (float*)d_out;
  float* out2 = out1 + (size_t)NROWS * XD;

  float* wsf = (float*)d_ws;
  size_t off = 0;
  float* w_     = wsf + off; off += NROWS;
  float* kv     = wsf + off; off += 16;
  float* u_mean = wsf + off; off += XD;
  float* u_inv  = wsf + off; off += XD;
  float* v_mean = wsf + off; off += DD;
  float* v_inv  = wsf + off; off += DD;
  float* p1u    = wsf + off; off += 64 * XD;
  float* p2u    = wsf + off; off += 64 * XD;
  float* p1v    = wsf + off; off += 64 * DD;
  float* p2v    = wsf + off; off += 64 * DD;

  size_t boff = (off * 4 + 255) & ~(size_t)255;
  unsigned short* W1Tu = (unsigned short*)((char*)d_ws + boff); boff += (size_t)(2 * XD) * XD * 2;
  unsigned short* W2Tu = (unsigned short*)((char*)d_ws + boff); boff += (size_t)XD * (2 * XD) * 2;
  unsigned short* W1Tv = (unsigned short*)((char*)d_ws + boff); boff += (size_t)(2 * DD) * DD * 2;
  unsigned short* W2Tv = (unsigned short*)((char*)d_ws + boff); boff += (size_t)DD * (2 * DD) * 2;
  size_t fixedB = (boff + 255) & ~(size_t)255;

  // choose chunk sizes by fit + grid-utilization cost
  static const int chs[7] = {16384, 8192, 4096, 2048, 1024, 512, 256};
  int CHu = 256, CHv = 256;
  double best = 1e30;
  for (int a = 0; a < 7; ++a)
    for (int b = 0; b < 7; ++b) {
      int cu = chs[a], cv = chs[b];
      size_t need = fixedB + (size_t)cu * XD * 6 + (size_t)cv * DD * 6 + 1024;
      if (need > ws_size) continue;
      auto util = [](int nwg) { return nwg >= 256 ? 1.0 : nwg / 256.0; };
      double cost = 68.75 / util((cu >> 8) * 8) + 68.75 / util((cu >> 8) * 4) +
                    550.0 / util((cv >> 8) * 32) + 550.0 / util((cv >> 8) * 16);
      if (cost < best) { best = cost; CHu = cu; CHv = cv; }
    }

  size_t p = fixedB;
  unsigned short* unc  = (unsigned short*)((char*)d_ws + p); p += (size_t)CHu * XD * 2;
  unsigned short* uhid = (unsigned short*)((char*)d_ws + p); p += (size_t)CHu * (2 * XD) * 2;
  unsigned short* vnc  = (unsigned short*)((char*)d_ws + p); p += (size_t)CHv * DD * 2;
  unsigned short* vhid = (unsigned short*)((char*)d_ws + p);

  // ---- stats ----
  mask_kernel<<<NROWS, 256, 0, stream>>>(u, v, w_);
  ksum_kernel<<<1, 256, 0, stream>>>(w_, kv);
  colstats_partial<<<dim3(XD / 256, 64), 256, 0, stream>>>(u, XD, w_, p1u, p2u);
  colstats_partial<<<dim3(DD / 256, 64), 256, 0, stream>>>(v, DD, w_, p1v, p2v);
  colstats_final<<<XD / 256, 256, 0, stream>>>(p1u, p2u, kv, XD, u_mean, u_inv);
  colstats_final<<<DD / 256, 256, 0, stream>>>(p1v, p2v, kv, DD, v_mean, v_inv);

  // ---- weights -> bf16 transposed ----
  wt_kernel<<<dim3(XD / 64, (2 * XD) / 64), 256, 0, stream>>>(u_W1, XD, 2 * XD, W1Tu);
  wt_kernel<<<dim3((2 * XD) / 64, XD / 64), 256, 0, stream>>>(u_W2, 2 * XD, XD, W2Tu);
  wt_kernel<<<dim3(DD / 64, (2 * DD) / 64), 256, 0, stream>>>(v_W1, DD, 2 * DD, W1Tv);
  wt_kernel<<<dim3((2 * DD) / 64, DD / 64), 256, 0, stream>>>(v_W2, 2 * DD, DD, W2Tv);

  // ---- u path ----
  for (int r0 = 0; r0 < NROWS; r0 += CHu) {
    size_t n8 = (size_t)CHu * XD / 8;
    int ng = (int)(n8 / 256 < 2048 ? n8 / 256 : 2048);
    norm_kernel<<<ng, 256, 0, stream>>>(u + (size_t)r0 * XD, u_mean, u_inv, unc, XD / 8 - 1, n8);
    gemm8p<0><<<(CHu >> 8) * ((2 * XD) >> 8), 512, 0, stream>>>(unc, W1Tu, u_b1, nullptr, uhid,
                                                                2 * XD, XD);
    gemm8p<1><<<(CHu >> 8) * (XD >> 8), 512, 0, stream>>>(uhid, W2Tu, u_b2, w_ + r0,
                                                          out1 + (size_t)r0 * XD, XD, 2 * XD);
  }
  // ---- v path ----
  for (int r0 = 0; r0 < NROWS; r0 += CHv) {
    size_t n8 = (size_t)CHv * DD / 8;
    int ng = (int)(n8 / 256 < 2048 ? n8 / 256 : 2048);
    norm_kernel<<<ng, 256, 0, stream>>>(v + (size_t)r0 * DD, v_mean, v_inv, vnc, DD / 8 - 1, n8);
    gemm8p<0><<<(CHv >> 8) * ((2 * DD) >> 8), 512, 0, stream>>>(vnc, W1Tv, v_b1, nullptr, vhid,
                                                                2 * DD, DD);
    gemm8p<1><<<(CHv >> 8) * (DD >> 8), 512, 0, stream>>>(vhid, W2Tv, v_b2, w_ + r0,
                                                          out2 + (size_t)r0 * DD, DD, 2 * DD);
  }
}